// Round 2
// baseline (376.732 us; speedup 1.0000x reference)
//
#include <hip/hip_runtime.h>
#include <hip/hip_fp8.h>
#include <stdint.h>

#define K_DIM 4096
#define N_DIM 4096
#define NKB   32      // 128-wide scale blocks along K
#define NTILE 64      // K-tiles of 64

using f32x4 = __attribute__((ext_vector_type(4))) float;

#define GLOAD_LDS16(g, l)                                                      \
    __builtin_amdgcn_global_load_lds(                                          \
        (const __attribute__((address_space(1))) unsigned int*)(g),            \
        (__attribute__((address_space(3))) unsigned int*)(l), 16, 0, 0)
#define GLOAD_LDS4(g, l)                                                       \
    __builtin_amdgcn_global_load_lds(                                          \
        (const __attribute__((address_space(1))) unsigned int*)(g),            \
        (__attribute__((address_space(3))) unsigned int*)(l), 4, 0, 0)

__device__ __forceinline__ uint8_t to_fp8(float v) {
    __hip_fp8_e4m3 q(v);
    return (uint8_t)q.__x;
}

// ---------------- activation quant: one wave per (m, kb); sa stored TRANSPOSED sa[kb][m] ----------------
__global__ __launch_bounds__(256) void act_quant_kernel(
    const float* __restrict__ x, uint8_t* __restrict__ xq,
    float* __restrict__ saT, int M)
{
    int gw   = blockIdx.x * 4 + (threadIdx.x >> 6);
    int lane = threadIdx.x & 63;
    int m    = gw >> 5;
    int kb   = gw & 31;
    size_t base = (size_t)m * K_DIM + kb * 128 + lane * 2;
    float2 v = *(const float2*)(x + base);
    float amax = fmaxf(fabsf(v.x), fabsf(v.y));
    #pragma unroll
    for (int o = 32; o >= 1; o >>= 1) amax = fmaxf(amax, __shfl_xor(amax, o));
    float s = amax / 448.0f;
    uchar2 q;
    q.x = to_fp8(v.x / s);
    q.y = to_fp8(v.y / s);
    *(uchar2*)(xq + base) = q;
    if (lane == 0) saT[(size_t)kb * M + m] = s;
}

// ---------------- weight quant ----------------
__global__ __launch_bounds__(256) void w_quant_kernel(
    const float* __restrict__ w, uint8_t* __restrict__ wq)
{
    size_t i = ((size_t)blockIdx.x * 256 + threadIdx.x) * 4;
    float4 v = *(const float4*)(w + i);
    uchar4 q;
    q.x = to_fp8(v.x); q.y = to_fp8(v.y); q.z = to_fp8(v.z); q.w = to_fp8(v.w);
    *(uchar4*)(wq + i) = q;
}

// ---------------- ratio pre-kernel ----------------
// ra[sb][m], sb=0..32: sb==0 -> 1; 1..31 -> sa[sb-1][m]/sa[sb][m]; 32 -> sa[31][m]
// rw[sb][nb] same recurrence over ws[nb][kb]
__global__ __launch_bounds__(256) void ratio_kernel(
    const float* __restrict__ saT, const float* __restrict__ ws,
    float* __restrict__ ra, float* __restrict__ rw, int M)
{
    int idx = blockIdx.x * 256 + threadIdx.x;
    if (idx < 33 * M) {
        int sb = idx / M, m = idx % M;
        float v;
        if (sb == 0)       v = 1.0f;
        else if (sb == 32) v = saT[(size_t)31 * M + m];
        else               v = saT[(size_t)(sb - 1) * M + m] / saT[(size_t)sb * M + m];
        ra[idx] = v;
    }
    if (idx < 33 * 32) {
        int sb = idx >> 5, nb = idx & 31;
        float v;
        if (sb == 0)       v = 1.0f;
        else if (sb == 32) v = ws[nb * NKB + 31];
        else               v = ws[nb * NKB + sb - 1] / ws[nb * NKB + sb];
        rw[idx] = v;
    }
}

// ---------------- fp8 block-scaled GEMM: 256x256 tile, BK=64, 3-buffer counted pipeline ----------------
#define LA0 0
#define LA1 16384
#define LA2 32768
#define LB0 49152
#define LB1 65536
#define LB2 81920
#define RA_OFF 98304
#define RW_OFF 99328

__global__ __launch_bounds__(512, 2) void fp8_gemm_pipe(
    const uint8_t* __restrict__ Aq, const uint8_t* __restrict__ Bq,
    const float* __restrict__ raP, const float* __restrict__ rwP,
    float* __restrict__ C, int M)
{
    __shared__ __align__(16) uint8_t lds[99456];

    const int tid  = threadIdx.x;
    const int lane = tid & 63;
    const int lr   = lane & 15;
    const int lk   = lane >> 4;
    const int wid  = tid >> 6;
    const int wm   = wid >> 2;          // 0..1
    const int wn   = wid & 3;           // 0..3

    // grid: (M/256) x 16 ; bijective XCD swizzle (nwg = 512, %8 == 0)
    const int gridN = N_DIM / 256;      // 16
    int nwg = (M / 256) * gridN;
    int cpx = nwg >> 3;
    int bid = blockIdx.x;
    int swz = (bid & 7) * cpx + (bid >> 3);
    const int m0 = (swz / gridN) * 256;
    const int n0 = (swz % gridN) * 256;
    const int nb = (n0 + wn * 64) >> 7; // weight-scale row block for this wave

    // staging map: thread -> (row, 16B slot), source pre-swizzled (slot ^ (row&3))
    const int srow   = tid >> 2;                 // 0..127
    const int scol16 = (tid & 3) ^ (srow & 3);
    const size_t gA0 = (size_t)(m0 + srow)       * K_DIM + scol16 * 16;
    const size_t gA1 = (size_t)(m0 + srow + 128) * K_DIM + scol16 * 16;
    const size_t gB0 = (size_t)(n0 + srow)       * K_DIM + scol16 * 16;
    const size_t gB1 = (size_t)(n0 + srow + 128) * K_DIM + scol16 * 16;
    const int ldsS0 = tid * 16;
    const int ldsS1 = 8192 + tid * 16;

    // fragment read offsets (swizzled): addr = row*64 + ((ks*32+lk*8) ^ ((row&3)<<4))
    const int swzlr = (lr & 3) << 4;
    const int aoff0 = (wm * 128 + lr) * 64 + ((lk * 8) ^ swzlr);
    const int aoff1 = (wm * 128 + lr) * 64 + ((32 + lk * 8) ^ swzlr);
    const int boff0 = (wn * 64 + lr) * 64 + ((lk * 8) ^ swzlr);
    const int boff1 = (wn * 64 + lr) * 64 + ((32 + lk * 8) ^ swzlr);

    f32x4 acc[8][4] = {};

    // ---- prologue: tiles 0 -> buf0, 1 -> buf1 (4 loads each) ----
    GLOAD_LDS16(Aq + gA0, &lds[LA0 + ldsS0]);
    GLOAD_LDS16(Bq + gB0, &lds[LB0 + ldsS0]);
    GLOAD_LDS16(Aq + gA1, &lds[LA0 + ldsS1]);
    GLOAD_LDS16(Bq + gB1, &lds[LB0 + ldsS1]);
    GLOAD_LDS16(Aq + gA0 + 64, &lds[LA1 + ldsS0]);
    GLOAD_LDS16(Bq + gB0 + 64, &lds[LB1 + ldsS0]);
    GLOAD_LDS16(Aq + gA1 + 64, &lds[LA1 + ldsS1]);
    GLOAD_LDS16(Bq + gB1 + 64, &lds[LB1 + ldsS1]);
    asm volatile("s_waitcnt vmcnt(4)" ::: "memory");
    __builtin_amdgcn_s_barrier();

#define TILE(CA, CB, EA, EB, TC, EVEN, S) do {                                  \
    const size_t kb = (size_t)((TC) & 63) * 64;                                 \
    long af[8], bf[4];                                                          \
    /* ---------- phase ks = 0 ---------- */                                    \
    _Pragma("unroll") for (int mi = 0; mi < 8; ++mi)                            \
        af[mi] = *(const long*)&lds[(CA) + aoff0 + mi * 1024];                  \
    _Pragma("unroll") for (int ni = 0; ni < 4; ++ni)                            \
        bf[ni] = *(const long*)&lds[(CB) + boff0 + ni * 1024];                  \
    f32x4 r4[8]; float rwc = 1.0f;                                              \
    if (EVEN && (S)) {                                                          \
        rwc = *(const float*)&lds[RW_OFF + nb * 4];                             \
        _Pragma("unroll") for (int mi = 0; mi < 8; ++mi)                        \
            r4[mi] = *(const f32x4*)&lds[RA_OFF + wm * 512 + mi * 64 + lk * 16];\
    }                                                                           \
    GLOAD_LDS16(Aq + gA0 + kb, &lds[(EA) + ldsS0]);                             \
    GLOAD_LDS16(Bq + gB0 + kb, &lds[(EB) + ldsS0]);                             \
    __builtin_amdgcn_s_barrier();                                               \
    asm volatile("s_waitcnt lgkmcnt(0)" ::: "memory");                          \
    __builtin_amdgcn_sched_barrier(0);                                          \
    if (EVEN && (S)) {                                                          \
        _Pragma("unroll") for (int mi = 0; mi < 8; ++mi) {                      \
            f32x4 sc = r4[mi] * rwc;                                            \
            _Pragma("unroll") for (int ni = 0; ni < 4; ++ni)                    \
                acc[mi][ni] *= sc;                                              \
        }                                                                       \
    }                                                                           \
    __builtin_amdgcn_s_setprio(1);                                              \
    _Pragma("unroll") for (int mi = 0; mi < 8; ++mi)                            \
        _Pragma("unroll") for (int ni = 0; ni < 4; ++ni)                        \
            acc[mi][ni] = __builtin_amdgcn_mfma_f32_16x16x32_fp8_fp8(           \
                af[mi], bf[ni], acc[mi][ni], 0, 0, 0);                          \
    __builtin_amdgcn_s_setprio(0);                                              \
    __builtin_amdgcn_s_barrier();                                               \
    /* ---------- phase ks = 1 ---------- */                                    \
    _Pragma("unroll") for (int mi = 0; mi < 8; ++mi)                            \
        af[mi] = *(const long*)&lds[(CA) + aoff1 + mi * 1024];                  \
    _Pragma("unroll") for (int ni = 0; ni < 4; ++ni)                            \
        bf[ni] = *(const long*)&lds[(CB) + boff1 + ni * 1024];                  \
    GLOAD_LDS16(Aq + gA1 + kb, &lds[(EA) + ldsS1]);                             \
    GLOAD_LDS16(Bq + gB1 + kb, &lds[(EB) + ldsS1]);                             \
    if (EVEN) {                                                                 \
        GLOAD_LDS4(raP + (size_t)((S) + 1) * M + m0 + wm * 128 + lane,          \
                   &lds[RA_OFF + wm * 512 + lane * 4]);                         \
        GLOAD_LDS4(raP + (size_t)((S) + 1) * M + m0 + wm * 128 + 64 + lane,     \
                   &lds[RA_OFF + wm * 512 + 256 + lane * 4]);                   \
        if (lane < 32)                                                          \
            GLOAD_LDS4(rwP + ((S) + 1) * 32 + lane, &lds[RW_OFF + lane * 4]);   \
    }                                                                           \
    __builtin_amdgcn_s_barrier();                                               \
    asm volatile("s_waitcnt lgkmcnt(0)" ::: "memory");                          \
    __builtin_amdgcn_sched_barrier(0);                                          \
    __builtin_amdgcn_s_setprio(1);                                              \
    _Pragma("unroll") for (int mi = 0; mi < 8; ++mi)                            \
        _Pragma("unroll") for (int ni = 0; ni < 4; ++ni)                        \
            acc[mi][ni] = __builtin_amdgcn_mfma_f32_16x16x32_fp8_fp8(           \
                af[mi], bf[ni], acc[mi][ni], 0, 0, 0);                          \
    __builtin_amdgcn_s_setprio(0);                                              \
    if (EVEN) { asm volatile("s_waitcnt vmcnt(7)" ::: "memory"); }              \
    else      { asm volatile("s_waitcnt vmcnt(4)" ::: "memory"); }              \
    __builtin_amdgcn_s_barrier();                                               \
} while (0)

    unsigned cA = LA0, cB = LB0, dA = LA1, dB = LB1, eA = LA2, eB = LB2, tp;
    for (int s = 0; s < 32; ++s) {
        TILE(cA, cB, eA, eB, 2 * s + 2, 1, s);
        tp = cA; cA = dA; dA = eA; eA = tp;
        tp = cB; cB = dB; dB = eB; eB = tp;
        TILE(cA, cB, eA, eB, 2 * s + 3, 0, s);
        tp = cA; cA = dA; dA = eA; eA = tp;
        tp = cB; cB = dB; dB = eB; eB = tp;
    }
#undef TILE

    // ---- epilogue: final absolute scale sa[31][m]*ws[nb][31] staged as ra[32]/rw[32] ----
    float rwf = *(const float*)&lds[RW_OFF + nb * 4];
    #pragma unroll
    for (int mi = 0; mi < 8; ++mi) {
        f32x4 rf = *(const f32x4*)&lds[RA_OFF + wm * 512 + mi * 64 + lk * 16];
        f32x4 sc = rf * rwf;
        #pragma unroll
        for (int j = 0; j < 4; ++j) {
            int m = m0 + wm * 128 + mi * 16 + lk * 4 + j;
            float* crow = C + (size_t)m * N_DIM + n0 + wn * 64;
            #pragma unroll
            for (int ni = 0; ni < 4; ++ni)
                crow[ni * 16 + lr] = acc[mi][ni][j] * sc[j];
        }
    }
}

extern "C" void kernel_launch(void* const* d_in, const int* in_sizes, int n_in,
                              void* d_out, int out_size, void* d_ws, size_t ws_size,
                              hipStream_t stream) {
    const float* x      = (const float*)d_in[0];
    const float* w      = (const float*)d_in[1];
    const float* wscale = (const float*)d_in[2];
    float* out = (float*)d_out;
    int M = in_sizes[0] / K_DIM;                  // 8192

    // workspace: xq [M*K] | wq [N*K] | saT [32*M] | ra [33*M] | rw [33*32]
    uint8_t* xq = (uint8_t*)d_ws;
    uint8_t* wq = xq + (size_t)M * K_DIM;
    float*   saT = (float*)(wq + (size_t)N_DIM * K_DIM);
    float*   ra  = saT + (size_t)NKB * M;
    float*   rw  = ra + (size_t)33 * M;

    act_quant_kernel<<<M * NKB / 4, 256, 0, stream>>>(x, xq, saT, M);
    w_quant_kernel<<<((size_t)N_DIM * K_DIM) / 1024, 256, 0, stream>>>(w, wq);
    ratio_kernel<<<(33 * M + 255) / 256, 256, 0, stream>>>(saT, wscale, ra, rw, M);

    int nwg = (M / 256) * (N_DIM / 256);
    fp8_gemm_pipe<<<nwg, 512, 0, stream>>>(xq, wq, ra, rw, out, M);
}

// Round 3
// 289.379 us; speedup vs baseline: 1.3019x; 1.3019x over previous
//
#include <hip/hip_runtime.h>
#include <hip/hip_fp8.h>
#include <stdint.h>

#define K_DIM 4096
#define N_DIM 4096
#define NKB   32     // number of 128-wide K scale blocks

using f32x4 = __attribute__((ext_vector_type(4))) float;
using i32x4 = __attribute__((ext_vector_type(4))) int;
using i32x8 = __attribute__((ext_vector_type(8))) int;

// async global->LDS, 16B per lane, linear dest (wave-uniform base + lane*16)
#define GLOAD_LDS16(g, l)                                                      \
    __builtin_amdgcn_global_load_lds(                                          \
        (const __attribute__((address_space(1))) unsigned int*)(g),            \
        (__attribute__((address_space(3))) unsigned int*)(l), 16, 0, 0)

__device__ __forceinline__ uint8_t to_fp8(float v) {
    __hip_fp8_e4m3 q(v);   // OCP e4m3fn, RNE saturating (gfx950 HW cvt)
    return (uint8_t)q.__x;
}

// ---------------- activation quant: one wave per (m, kb) ----------------
__global__ __launch_bounds__(256) void act_quant_kernel(
    const float* __restrict__ x, uint8_t* __restrict__ xq,
    float* __restrict__ sa)
{
    int gw   = blockIdx.x * 4 + (threadIdx.x >> 6);
    int lane = threadIdx.x & 63;
    int m    = gw >> 5;
    int kb   = gw & 31;
    size_t base = (size_t)m * K_DIM + kb * 128 + lane * 2;
    float2 v = *(const float2*)(x + base);
    float amax = fmaxf(fabsf(v.x), fabsf(v.y));
    #pragma unroll
    for (int o = 32; o >= 1; o >>= 1) amax = fmaxf(amax, __shfl_xor(amax, o));
    float s = amax / 448.0f;          // IEEE div, matches jnp exactly
    uchar2 q;
    q.x = to_fp8(v.x / s);
    q.y = to_fp8(v.y / s);
    *(uchar2*)(xq + base) = q;
    if (lane == 0) sa[(size_t)m * NKB + kb] = s;
}

// ---------------- weight quant: f32 (exact fp8 values) -> bytes ----------------
__global__ __launch_bounds__(256) void w_quant_kernel(
    const float* __restrict__ w, uint8_t* __restrict__ wq)
{
    size_t i = ((size_t)blockIdx.x * 256 + threadIdx.x) * 4;
    float4 v = *(const float4*)(w + i);
    uchar4 q;
    q.x = to_fp8(v.x); q.y = to_fp8(v.y); q.z = to_fp8(v.z); q.w = to_fp8(v.w);
    *(uchar4*)(wq + i) = q;
}

// ---------------- MX fp8 block-scaled GEMM ----------------
// 128x128 tile, BK=128 (= one scale block per iteration), 4 waves of 64x64.
// One mfma_scale_f32_16x16x128_f8f6f4 (unit e8m0 scales) per fragment per
// K-block -> exact f32 block-sum; per-row f32 scale applied on VALU.
__global__ __launch_bounds__(256) void fp8_gemm_mx(
    const uint8_t* __restrict__ Aq, const uint8_t* __restrict__ Bq,
    const float* __restrict__ sa, const float* __restrict__ wscale,
    float* __restrict__ C, int mTiles)
{
    __shared__ __align__(16) uint8_t lA[128 * 128];
    __shared__ __align__(16) uint8_t lB[128 * 128];
    __shared__ float lS[128];

    const int t    = threadIdx.x;
    const int lane = t & 63;
    const int wid  = t >> 6;
    const int lr   = lane & 15;
    const int lk   = lane >> 4;          // 0..3 -> k sub-block of 32
    const int wr   = (wid >> 1) * 64;    // wave row offset
    const int wc   = (wid & 1) * 64;     // wave col offset

    const int nTiles = N_DIM / 128;      // 32
    int nwg = mTiles * nTiles;           // 2048, %8==0
    int cpx = nwg >> 3;
    int bid = blockIdx.x;
    int swz = (bid & 7) * cpx + (bid >> 3);   // bijective XCD swizzle
    int mT = swz / nTiles, nT = swz % nTiles;
    const int m0 = mT * 128, n0 = nT * 128;

    // staging map: thread t -> row srow, phys 16B chunk (t&7); source column is
    // the logical chunk ((t&7) ^ (srow&7)) so that linear LDS dest ends up
    // chunk-swizzled: phys_chunk = logical_chunk ^ (row&7).
    const int srow = t >> 3;                      // 0..31 per pass
    const int lcol = ((t & 7) ^ (srow & 7)) * 16;
    const uint8_t* gA = Aq + (size_t)(m0 + srow) * K_DIM + lcol;
    const uint8_t* gB = Bq + (size_t)(n0 + srow) * K_DIM + lcol;
    const int ldst = t * 16;

    // fragment read: lane (lr,lk) reads logical bytes [lk*32, lk*32+32) of its
    // row; rows wr/wc + mi*16 + lr  ->  (row&7) == (lr&7)
    const int fswz = (lr & 7) << 4;
    const int c0 = (lk * 32) ^ fswz;
    const int c1 = (lk * 32 + 16) ^ fswz;

    f32x4 acc[4][4] = {};
    const f32x4 vzero = {0.f, 0.f, 0.f, 0.f};

    for (int kb = 0; kb < NKB; ++kb) {
        // ---- stage A,B tiles: 4 passes x 256 threads x 16B = 16KB each ----
        size_t ko = (size_t)kb * 128;
        #pragma unroll
        for (int i = 0; i < 4; ++i) {
            GLOAD_LDS16(gA + ko + (size_t)i * 32 * K_DIM, &lA[i * 4096 + ldst]);
            GLOAD_LDS16(gB + ko + (size_t)i * 32 * K_DIM, &lB[i * 4096 + ldst]);
        }
        if (t < 128)
            lS[t] = sa[(size_t)(m0 + t) * NKB + kb] * wscale[nT * NKB + kb];
        __syncthreads();

        // ---- load fragments (2x ds_read_b128 per fragment) ----
        i32x8 af[4], bf[4];
        #pragma unroll
        for (int mi = 0; mi < 4; ++mi) {
            int ab = (wr + mi * 16 + lr) * 128;
            i32x4 lo = *(const i32x4*)&lA[ab + c0];
            i32x4 hi = *(const i32x4*)&lA[ab + c1];
            af[mi][0] = lo[0]; af[mi][1] = lo[1]; af[mi][2] = lo[2]; af[mi][3] = lo[3];
            af[mi][4] = hi[0]; af[mi][5] = hi[1]; af[mi][6] = hi[2]; af[mi][7] = hi[3];
        }
        #pragma unroll
        for (int ni = 0; ni < 4; ++ni) {
            int bb = (wc + ni * 16 + lr) * 128;
            i32x4 lo = *(const i32x4*)&lB[bb + c0];
            i32x4 hi = *(const i32x4*)&lB[bb + c1];
            bf[ni][0] = lo[0]; bf[ni][1] = lo[1]; bf[ni][2] = lo[2]; bf[ni][3] = lo[3];
            bf[ni][4] = hi[0]; bf[ni][5] = hi[1]; bf[ni][6] = hi[2]; bf[ni][7] = hi[3];
        }

        // ---- 16 independent K=128 MFMAs + per-row scale accumulate ----
        #pragma unroll
        for (int mi = 0; mi < 4; ++mi) {
            f32x4 s4 = *(const f32x4*)&lS[wr + mi * 16 + lk * 4];
            f32x4 bs[4];
            #pragma unroll
            for (int ni = 0; ni < 4; ++ni)
                bs[ni] = __builtin_amdgcn_mfma_scale_f32_16x16x128_f8f6f4(
                    af[mi], bf[ni], vzero, 0, 0,
                    0, 0x7F7F7F7F, 0, 0x7F7F7F7F);   // unit scales (e8m0 127)
            #pragma unroll
            for (int ni = 0; ni < 4; ++ni)
                acc[mi][ni] += bs[ni] * s4;
        }
        __syncthreads();
    }

    // ---- epilogue: C/D layout col=lane&15, row=lk*4+j (verified R1) ----
    #pragma unroll
    for (int mi = 0; mi < 4; ++mi) {
        #pragma unroll
        for (int j = 0; j < 4; ++j) {
            int m = m0 + wr + mi * 16 + lk * 4 + j;
            float* crow = C + (size_t)m * N_DIM + n0 + wc;
            #pragma unroll
            for (int ni = 0; ni < 4; ++ni)
                crow[ni * 16 + lr] = acc[mi][ni][j];
        }
    }
}

extern "C" void kernel_launch(void* const* d_in, const int* in_sizes, int n_in,
                              void* d_out, int out_size, void* d_ws, size_t ws_size,
                              hipStream_t stream) {
    const float* x      = (const float*)d_in[0];
    const float* w      = (const float*)d_in[1];
    const float* wscale = (const float*)d_in[2];
    float* out = (float*)d_out;
    int M = in_sizes[0] / K_DIM;                  // 8192

    // workspace layout: xq [M*K] | wq [N*K] | sa [M*32] f32
    uint8_t* xq = (uint8_t*)d_ws;
    uint8_t* wq = xq + (size_t)M * K_DIM;
    float*   sa = (float*)(wq + (size_t)N_DIM * K_DIM);

    act_quant_kernel<<<M * NKB / 4, 256, 0, stream>>>(x, xq, sa);
    w_quant_kernel<<<((size_t)N_DIM * K_DIM) / 1024, 256, 0, stream>>>(w, wq);

    int mTiles = M / 128;
    fp8_gemm_mx<<<mTiles * (N_DIM / 128), 256, 0, stream>>>(
        xq, wq, sa, wscale, out, mTiles);
}